// Round 9
// baseline (209.710 us; speedup 1.0000x reference)
//
#include <hip/hip_runtime.h>
#include <hip/hip_bf16.h>

// Problem constants
#define QSTRIDE 147584   // per-sample question_rep stride (128*128*9 + 128)
#define WOFF    147456   // bias offset within question_rep row

typedef __attribute__((ext_vector_type(8))) short bf16x8;
typedef __attribute__((ext_vector_type(4))) float f32x4;

static __device__ __forceinline__ ushort f2bf(float f) {
  union { float f; unsigned u; } x; x.f = f;
  unsigned r = x.u + 0x7fffu + ((x.u >> 16) & 1u);  // RNE bf16 (finite inputs)
  return (ushort)(r >> 16);
}
static __device__ __forceinline__ unsigned pk2(ushort a, ushort b) {
  return (unsigned)a | ((unsigned)b << 16);
}

// ---------------------------------------------------------------------------
// 1) MERGED prep kernel, occupancy-fixed: smem union is now 18,432 B
//    (was 55,296) -> 8 blocks/CU for every branch. Block ranges:
//      [0,1024)     transpose_x : lhs/rhs fp32 NCHW -> xt[b][c8][px1024][ch32]
//      [1024,2048)  pack_w v3   : 8-o blocks, DIRECT float4 global reads
//                   (each block reads its 36,864 B exactly once, no Ls,
//                   no read barriers), Lw fragment image in LDS, dumped as
//                   512B-contiguous/wave uint2 stores.
//      [2048,2064)  pack_pw     : proj_w -> pwb2[chunk][o][c32]
// ---------------------------------------------------------------------------
__global__ __launch_bounds__(256) void prep_kernel(const float* __restrict__ q,
                                                   const float* __restrict__ pw,
                                                   const float* __restrict__ lhs,
                                                   const float* __restrict__ rhs,
                                                   ushort* __restrict__ wt2,
                                                   ushort* __restrict__ pwb2,
                                                   ushort* __restrict__ xt) {
  __shared__ __attribute__((aligned(16))) char smem[18432];
  int blk = blockIdx.x;
  int t = threadIdx.x;

  if (blk < 1024) {
    // ---- transpose_x (verified R6 body; now 8 blocks/CU) ----
    ushort (*Ts)[132] = (ushort(*)[132])smem;      // 8448 B
    int b = blk >> 4, x = blk & 15;
    int c = x & 7, half = x >> 3;
    const float* src = (c < 4 ? lhs : rhs) + (size_t)b * 131072 + (size_t)(c & 3) * 32768;
    ushort* dst = xt + (size_t)(b * 8 + c) * 32768;
    int chw = t >> 3, pxg = (t & 7) * 16;
    int pxr = t >> 1, chr = (t & 1) * 16;
#pragma unroll
    for (int pt = 0; pt < 4; ++pt) {
      int p0 = half * 512 + pt * 128;
      if (pt) __syncthreads();
      const float* s = src + (size_t)chw * 1024 + p0 + pxg;
#pragma unroll
      for (int i = 0; i < 4; ++i) {
        float4 f = *(const float4*)(s + 4 * i);
        uint2 pk;
        pk.x = pk2(f2bf(f.x), f2bf(f.y));
        pk.y = pk2(f2bf(f.z), f2bf(f.w));
        *(uint2*)&Ts[chw][pxg + 4 * i] = pk;
      }
      __syncthreads();
      ushort g[16];
#pragma unroll
      for (int j = 0; j < 16; ++j) g[j] = Ts[chr + j][pxr];
      *(uint4*)(dst + (size_t)(p0 + pxr) * 32 + chr)     = *(uint4*)&g[0];
      *(uint4*)(dst + (size_t)(p0 + pxr) * 32 + chr + 8) = *(uint4*)&g[8];
    }
  } else if (blk < 2048) {
    // ---- pack_w v3: 8-o block, direct global float4 reads ----
    ushort* Lw = (ushort*)smem;                    // [9][4][8][32] = 18,432 B
    int idx = blk - 1024;
    int b = idx >> 4, og = idx & 15;               // 16 o-groups of 8
    int o_loc = t >> 5, c4 = t & 31;               // thread: (o, 4 channels)
    int ci0 = c4 * 4;
    int cq = ci0 >> 5, coff = ci0 & 31;
    // 36 consecutive floats = w[o][ci0..ci0+3][tap0..8]; 16B-aligned (c4*144B)
    const float4* src = (const float4*)(q + (size_t)b * QSTRIDE
                          + (size_t)(og * 8 + o_loc) * 1152 + (size_t)ci0 * 9);
    float4 ff[9];
#pragma unroll
    for (int i = 0; i < 9; ++i) ff[i] = src[i];
    const float* v = (const float*)ff;
#pragma unroll
    for (int tap = 0; tap < 9; ++tap) {
      uint2 pkv;
      pkv.x = pk2(f2bf(v[tap]),      f2bf(v[9 + tap]));
      pkv.y = pk2(f2bf(v[18 + tap]), f2bf(v[27 + tap]));
      *(uint2*)&Lw[((tap * 4 + cq) * 8 + o_loc) * 32 + coff] = pkv;
    }
    __syncthreads();
    // dump: wave wv handles (tap, cq=wv), 9 chunks x 512 B contiguous
    int wv = t >> 6, l = t & 63;
    ushort* dstb = wt2 + (size_t)b * 147456 + (size_t)og * 256;
#pragma unroll
    for (int tap = 0; tap < 9; ++tap) {
      uint2 val = *(const uint2*)&Lw[(tap * 4 + wv) * 256 + l * 4];
      *(uint2*)(dstb + (size_t)(tap * 4 + wv) * 4096 + l * 4) = val;
    }
  } else {
    // ---- pack_pw (verified body) ----
    int tg = (blk - 2048) * 256 + t;
    int o  = tg >> 5;
    int c0 = (tg & 31) * 8;
    const float4* s4 = (const float4*)(pw + (size_t)o * 256 + c0);
    float4 f0 = s4[0], f1 = s4[1];
    uint4 pkv;
    pkv.x = pk2(f2bf(f0.x), f2bf(f0.y)); pkv.y = pk2(f2bf(f0.z), f2bf(f0.w));
    pkv.z = pk2(f2bf(f1.x), f2bf(f1.y)); pkv.w = pk2(f2bf(f1.z), f2bf(f1.w));
    *(uint4*)(pwb2 + (size_t)(c0 >> 5) * 4096 + o * 32 + (c0 & 31)) = pkv;
  }
}

// ---------------------------------------------------------------------------
// 2) FUSED proj+conv, 2-row tiles for occupancy: grid 1024 (64 b x 16 tiles),
//    Bs[4][4][34][32] = 34,816 B, launch_bounds(256,4) -> 4 blocks/CU
//    (16 waves/CU, 2x the latency-hiding pool of the R6 version).
//    Staggered blocks overlap phase-1 loads with phase-2 MFMAs.
//    phase 1: wave owns patch row wv (rows h0-1..h0+2), acc[2][8].
//    phase 2: wave owns 64o x 32px, acc2[4][2]; A-frags from L2-hot wt2
//    (all 16 same-b blocks land on one XCD: b = blk & 63, 64 % 8 == 0).
// ---------------------------------------------------------------------------
__global__ __launch_bounds__(256, 4) void fused_conv_kernel(const ushort* __restrict__ wt2,
                                                            const ushort* __restrict__ pwb2,
                                                            const ushort* __restrict__ xt,
                                                            const float* __restrict__ pb,
                                                            const float* __restrict__ q,
                                                            float* __restrict__ out) {
  __shared__ ushort Bs[4][4][34][32];        // 34,816 B
  int blk = blockIdx.x;
  int b = blk & 63, tile = blk >> 6;         // tile 0..15
  int p0 = tile * 64, h0 = tile * 2;
  int t = threadIdx.x;
  int lane = t & 63, wv = t >> 6;
  int quad = lane >> 4, li = lane & 15;

  // ---- col-halo zero: px 0 and 33 of every (cq, row) ----
  if (t < 32) {
    int cq = t & 3, side = (t >> 2) & 1, rr = t >> 3;   // rr 0..3
    uint4* z4 = (uint4*)&Bs[cq][rr][side ? 33 : 0][0];
    uint4 z; z.x = z.y = z.z = z.w = 0u;
    z4[0] = z; z4[1] = z; z4[2] = z; z4[3] = z;
  }

  // ---- phase 1: mini-proj into Bs (wave wv owns patch row wv) ----
  {
    int h = h0 - 1 + wv;                     // image row for this wave
    bool lv = (h >= 0) && (h < 32);
    const ushort* xtb = xt + (size_t)b * 8 * 32768;
    f32x4 acc[2][8] = {};
#pragma unroll
    for (int c = 0; c < 8; ++c) {            // 8 chunks of 32 channels
      bf16x8 bg[2];
#pragma unroll
      for (int k = 0; k < 2; ++k) {
        union { uint4 u; bf16x8 v; } bu;
        if (lv) {
          int px = h * 32 + k * 16 + li;
          bu.u = *(const uint4*)(xtb + ((size_t)c * 1024 + px) * 32 + quad * 8);
        } else {
          bu.u.x = bu.u.y = bu.u.z = bu.u.w = 0u;
        }
        bg[k] = bu.v;
      }
      const ushort* ap = pwb2 + (size_t)c * 4096 + li * 32 + quad * 8;
#pragma unroll
      for (int mi = 0; mi < 8; ++mi) {
        bf16x8 af = *(const bf16x8*)(ap + mi * 512);   // reused for both k
#pragma unroll
        for (int k = 0; k < 2; ++k)
          acc[k][mi] = __builtin_amdgcn_mfma_f32_16x16x32_bf16(af, bg[k], acc[k][mi], 0, 0, 0);
      }
    }
    // epilogue -> Bs (live rows: +bias; dead rows: zeros -- conv zero-padding)
#pragma unroll
    for (int k = 0; k < 2; ++k) {
#pragma unroll
      for (int mi = 0; mi < 8; ++mi) {
        int o0 = mi * 16 + quad * 4;
        uint2 pkv;
        if (lv) {
          float4 bias = *(const float4*)(pb + o0);
          f32x4 a = acc[k][mi];
          pkv.x = pk2(f2bf(a.x + bias.x), f2bf(a.y + bias.y));
          pkv.y = pk2(f2bf(a.z + bias.z), f2bf(a.w + bias.w));
        } else {
          pkv.x = 0u; pkv.y = 0u;
        }
        *(uint2*)&Bs[o0 >> 5][wv][k * 16 + li + 1][o0 & 31] = pkv;
      }
    }
  }
  __syncthreads();                           // Bs fully built & visible

  // ---- phase 2: 3x3 conv over Bs, A-frags from wt2 global (L2-hot) ----
  int m0 = (wv & 1) * 64, n0 = (wv >> 1) * 32;
  f32x4 acc2[4][2] = {};
  const ushort* wtb = wt2 + (size_t)b * 147456;
#pragma unroll
  for (int cq = 0; cq < 4; ++cq) {
    const ushort* wcq = wtb + (size_t)cq * 4096;
#pragma unroll
    for (int tap = 0; tap < 9; ++tap) {
      const ushort* ar = wcq + (size_t)tap * 16384;   // slab (tap*4+cq)*4096
      int kh = tap / 3, kw = tap - kh * 3;
      bf16x8 af[4], bg[2];
#pragma unroll
      for (int mi = 0; mi < 4; ++mi)
        af[mi] = *(const bf16x8*)(ar + (m0 + mi*16 + li) * 32 + quad * 8);
#pragma unroll
      for (int ni = 0; ni < 2; ++ni) {
        int pl = n0 + ni*16 + li;            // 0..63
        int hh = pl >> 5, ww = pl & 31;
        bg[ni] = *(const bf16x8*)&Bs[cq][hh + kh][ww + kw][quad * 8];
      }
#pragma unroll
      for (int mi = 0; mi < 4; ++mi)
#pragma unroll
        for (int ni = 0; ni < 2; ++ni)
          acc2[mi][ni] = __builtin_amdgcn_mfma_f32_16x16x32_bf16(af[mi], bg[ni], acc2[mi][ni], 0, 0, 0);
    }
  }

  const float* qb = q + (size_t)b * QSTRIDE + WOFF;
  float* ob = out + (size_t)b * 128 * 1024 + p0;
#pragma unroll
  for (int mi = 0; mi < 4; ++mi) {
    int o0 = m0 + mi*16 + quad*4;
    float4 bias = *(const float4*)(qb + o0);
#pragma unroll
    for (int ni = 0; ni < 2; ++ni) {
      int pl = n0 + ni*16 + li;
      float* dp = ob + (size_t)o0 * 1024 + pl;
      f32x4 a = acc2[mi][ni];
      dp[0]    = a.x + bias.x;
      dp[1024] = a.y + bias.y;
      dp[2048] = a.z + bias.z;
      dp[3072] = a.w + bias.w;
    }
  }
}

extern "C" void kernel_launch(void* const* d_in, const int* in_sizes, int n_in,
                              void* d_out, int out_size, void* d_ws, size_t ws_size,
                              hipStream_t stream) {
  const float* q   = (const float*)d_in[0];
  const float* lhs = (const float*)d_in[1];
  const float* rhs = (const float*)d_in[2];
  const float* pw  = (const float*)d_in[3];
  const float* pb  = (const float*)d_in[4];
  float* out = (float*)d_out;

  // workspace layout (52,494,336 B used)
  char* ws = (char*)d_ws;
  ushort* wt2  = (ushort*)(ws);               // 18,874,368 B : wt2[b][tap][cq][o][32]
  ushort* pwb2 = (ushort*)(ws + 18874368);    //     65,536 B : pwb2[chunk][o][32]
  ushort* xt   = (ushort*)(ws + 18939904);    // 33,554,432 B : xt[b][c8][px1024][ch32]

  prep_kernel      <<<2064, 256, 0, stream>>>(q, pw, lhs, rhs, wt2, pwb2, xt);
  fused_conv_kernel<<<1024, 256, 0, stream>>>(wt2, pwb2, xt, pb, q, out);
}

// Round 10
// 193.542 us; speedup vs baseline: 1.0835x; 1.0835x over previous
//
#include <hip/hip_runtime.h>
#include <hip/hip_bf16.h>

// Problem constants
#define QSTRIDE 147584   // per-sample question_rep stride (128*128*9 + 128)
#define WOFF    147456   // bias offset within question_rep row

typedef __attribute__((ext_vector_type(8))) short bf16x8;
typedef __attribute__((ext_vector_type(4))) float f32x4;

static __device__ __forceinline__ ushort f2bf(float f) {
  union { float f; unsigned u; } x; x.f = f;
  unsigned r = x.u + 0x7fffu + ((x.u >> 16) & 1u);  // RNE bf16 (finite inputs)
  return (ushort)(r >> 16);
}
static __device__ __forceinline__ unsigned pk2(ushort a, ushort b) {
  return (unsigned)a | ((unsigned)b << 16);
}

// ---------------------------------------------------------------------------
// 1) MERGED prep kernel -- FROZEN from R8 (prep + overhead measured stable
//    at ~136.6 us across R8/R9; fused is the isolated variable this round).
// ---------------------------------------------------------------------------
__global__ __launch_bounds__(256) void prep_kernel(const float* __restrict__ q,
                                                   const float* __restrict__ pw,
                                                   const float* __restrict__ lhs,
                                                   const float* __restrict__ rhs,
                                                   ushort* __restrict__ wt2,
                                                   ushort* __restrict__ pwb2,
                                                   ushort* __restrict__ xt) {
  __shared__ __attribute__((aligned(16))) char smem[18432];
  int blk = blockIdx.x;
  int t = threadIdx.x;

  if (blk < 1024) {
    // ---- transpose_x ----
    ushort (*Ts)[132] = (ushort(*)[132])smem;      // 8448 B
    int b = blk >> 4, x = blk & 15;
    int c = x & 7, half = x >> 3;
    const float* src = (c < 4 ? lhs : rhs) + (size_t)b * 131072 + (size_t)(c & 3) * 32768;
    ushort* dst = xt + (size_t)(b * 8 + c) * 32768;
    int chw = t >> 3, pxg = (t & 7) * 16;
    int pxr = t >> 1, chr = (t & 1) * 16;
#pragma unroll
    for (int pt = 0; pt < 4; ++pt) {
      int p0 = half * 512 + pt * 128;
      if (pt) __syncthreads();
      const float* s = src + (size_t)chw * 1024 + p0 + pxg;
#pragma unroll
      for (int i = 0; i < 4; ++i) {
        float4 f = *(const float4*)(s + 4 * i);
        uint2 pk;
        pk.x = pk2(f2bf(f.x), f2bf(f.y));
        pk.y = pk2(f2bf(f.z), f2bf(f.w));
        *(uint2*)&Ts[chw][pxg + 4 * i] = pk;
      }
      __syncthreads();
      ushort g[16];
#pragma unroll
      for (int j = 0; j < 16; ++j) g[j] = Ts[chr + j][pxr];
      *(uint4*)(dst + (size_t)(p0 + pxr) * 32 + chr)     = *(uint4*)&g[0];
      *(uint4*)(dst + (size_t)(p0 + pxr) * 32 + chr + 8) = *(uint4*)&g[8];
    }
  } else if (blk < 2048) {
    // ---- pack_w v3 ----
    ushort* Lw = (ushort*)smem;                    // [9][4][8][32] = 18,432 B
    int idx = blk - 1024;
    int b = idx >> 4, og = idx & 15;
    int o_loc = t >> 5, c4 = t & 31;
    int ci0 = c4 * 4;
    int cq = ci0 >> 5, coff = ci0 & 31;
    const float4* src = (const float4*)(q + (size_t)b * QSTRIDE
                          + (size_t)(og * 8 + o_loc) * 1152 + (size_t)ci0 * 9);
    float4 ff[9];
#pragma unroll
    for (int i = 0; i < 9; ++i) ff[i] = src[i];
    const float* v = (const float*)ff;
#pragma unroll
    for (int tap = 0; tap < 9; ++tap) {
      uint2 pkv;
      pkv.x = pk2(f2bf(v[tap]),      f2bf(v[9 + tap]));
      pkv.y = pk2(f2bf(v[18 + tap]), f2bf(v[27 + tap]));
      *(uint2*)&Lw[((tap * 4 + cq) * 8 + o_loc) * 32 + coff] = pkv;
    }
    __syncthreads();
    int wv = t >> 6, l = t & 63;
    ushort* dstb = wt2 + (size_t)b * 147456 + (size_t)og * 256;
#pragma unroll
    for (int tap = 0; tap < 9; ++tap) {
      uint2 val = *(const uint2*)&Lw[(tap * 4 + wv) * 256 + l * 4];
      *(uint2*)(dstb + (size_t)(tap * 4 + wv) * 4096 + l * 4) = val;
    }
  } else {
    // ---- pack_pw ----
    int tg = (blk - 2048) * 256 + t;
    int o  = tg >> 5;
    int c0 = (tg & 31) * 8;
    const float4* s4 = (const float4*)(pw + (size_t)o * 256 + c0);
    float4 f0 = s4[0], f1 = s4[1];
    uint4 pkv;
    pkv.x = pk2(f2bf(f0.x), f2bf(f0.y)); pkv.y = pk2(f2bf(f0.z), f2bf(f0.w));
    pkv.z = pk2(f2bf(f1.x), f2bf(f1.y)); pkv.w = pk2(f2bf(f1.z), f2bf(f1.w));
    *(uint4*)(pwb2 + (size_t)(c0 >> 5) * 4096 + o * 32 + (c0 & 31)) = pkv;
  }
}

// ---------------------------------------------------------------------------
// 2) FUSED proj+conv (R6/R8 4-row structure) + MANUAL DEPTH-2 REGISTER
//    SOFTWARE PIPELINE in both phases. Evidence: VGPR_Count=112 of a 256
//    budget showed the compiler never pipelined the barrier-free unrolled
//    loops -- per-step load latency chains (L2 ~200cy, xt ~300-900cy) were
//    serial with only 2 waves/SIMD to interleave. Fragments for iter i+2 are
//    loaded into a 3-stage register ring (compile-time indices after unroll)
//    BEFORE iter i's MFMA cluster; sched_barrier(0) pins the issue order.
//    Math order bit-identical to R8.
// ---------------------------------------------------------------------------
__global__ __launch_bounds__(256, 2) void fused_conv_kernel(const ushort* __restrict__ wt2,
                                                            const ushort* __restrict__ pwb2,
                                                            const ushort* __restrict__ xt,
                                                            const float* __restrict__ pb,
                                                            const float* __restrict__ q,
                                                            float* __restrict__ out) {
  __shared__ ushort Bs[4][6][34][32];        // 52,224 B
  int blk = blockIdx.x;
  int b = blk & 63, tile = blk >> 6;
  int p0 = tile * 128, h0 = tile * 4;
  int t = threadIdx.x;
  int lane = t & 63, wv = t >> 6;
  int quad = lane >> 4, li = lane & 15;

  // ---- col-halo zero: px 0 and 33 of every (cq, row) ----
  if (t < 48) {
    int cq = t & 3, side = (t >> 2) & 1, rr = t >> 3;   // rr 0..5
    uint4* z4 = (uint4*)&Bs[cq][rr][side ? 33 : 0][0];
    uint4 z; z.x = z.y = z.z = z.w = 0u;
    z4[0] = z; z4[1] = z; z4[2] = z; z4[3] = z;
  }

  // ---- phase 1: mini-proj into Bs, depth-2 pipelined ----
  {
    int rk[3], wk[3], hk[3]; bool lv[3];
#pragma unroll
    for (int k = 0; k < 3; ++k) {
      int nt = wv * 3 + k;
      rk[k] = nt >> 1;                       // Bs row 0..5
      wk[k] = (nt & 1) * 16;                 // w base 0 or 16
      hk[k] = h0 - 1 + rk[k];                // image row
      lv[k] = (hk[k] >= 0) && (hk[k] < 32);
    }
    const ushort* xtb = xt + (size_t)b * 8 * 32768;
    f32x4 acc[3][8] = {};
    bf16x8 bgp[3][3];                        // bg ring: depth 2
    bf16x8 afp[2][8];                        // af ring: depth 1 (pwb2 L1/L2-hot)

#define LOADBG(cc, st) do { \
    _Pragma("unroll") \
    for (int k = 0; k < 3; ++k) { \
      union { uint4 u; bf16x8 v; } bu; \
      if (lv[k]) { \
        int px = hk[k] * 32 + wk[k] + li; \
        bu.u = *(const uint4*)(xtb + ((size_t)(cc) * 1024 + px) * 32 + quad * 8); \
      } else { bu.u.x = bu.u.y = bu.u.z = bu.u.w = 0u; } \
      bgp[st][k] = bu.v; \
    } } while (0)
#define LOADAF(cc, st) do { \
    const ushort* ap_ = pwb2 + (size_t)(cc) * 4096 + li * 32 + quad * 8; \
    _Pragma("unroll") \
    for (int mi = 0; mi < 8; ++mi) afp[st][mi] = *(const bf16x8*)(ap_ + mi * 512); \
  } while (0)

    LOADBG(0, 0); LOADBG(1, 1);              // prologue: chunks 0,1 bg in flight
    LOADAF(0, 0);                            // chunk 0 af in flight
#pragma unroll
    for (int c = 0; c < 8; ++c) {
      if (c < 6) LOADBG(c + 2, (c + 2) % 3); // prefetch bg two chunks ahead
      if (c < 7) LOADAF(c + 1, (c + 1) & 1); // prefetch af one chunk ahead
      __builtin_amdgcn_sched_barrier(0);     // pin issues above the MFMA cluster
#pragma unroll
      for (int mi = 0; mi < 8; ++mi)
#pragma unroll
        for (int k = 0; k < 3; ++k)
          acc[k][mi] = __builtin_amdgcn_mfma_f32_16x16x32_bf16(afp[c & 1][mi], bgp[c % 3][k], acc[k][mi], 0, 0, 0);
    }
#undef LOADBG
#undef LOADAF

    // epilogue -> Bs (live rows: +bias; dead rows: zeros -- conv zero-padding)
#pragma unroll
    for (int k = 0; k < 3; ++k) {
#pragma unroll
      for (int mi = 0; mi < 8; ++mi) {
        int o0 = mi * 16 + quad * 4;
        uint2 pkv;
        if (lv[k]) {
          float4 bias = *(const float4*)(pb + o0);
          f32x4 a = acc[k][mi];
          pkv.x = pk2(f2bf(a.x + bias.x), f2bf(a.y + bias.y));
          pkv.y = pk2(f2bf(a.z + bias.z), f2bf(a.w + bias.w));
        } else {
          pkv.x = 0u; pkv.y = 0u;
        }
        *(uint2*)&Bs[o0 >> 5][rk[k]][wk[k] + li + 1][o0 & 31] = pkv;
      }
    }
  }
  __syncthreads();                           // Bs fully built & visible

  // ---- phase 2: 36 (cq,tap) steps, depth-2 pipelined, barrier-free ----
  int m0 = (wv & 1) * 64, n0 = (wv >> 1) * 64;
  f32x4 acc2[4][4] = {};
  const ushort* wtb = wt2 + (size_t)b * 147456;
  bf16x8 af2[3][4], bg2[3][4];               // 3-stage rings

#define LDA2(ss, st) do { \
    const int cq_ = (ss) / 9, tap_ = (ss) % 9; \
    const ushort* ar_ = wtb + (size_t)(tap_ * 4 + cq_) * 4096; \
    _Pragma("unroll") \
    for (int mi = 0; mi < 4; ++mi) \
      af2[st][mi] = *(const bf16x8*)(ar_ + (m0 + mi*16 + li) * 32 + quad * 8); \
  } while (0)
#define LDB2(ss, st) do { \
    const int cq_ = (ss) / 9, tap_ = (ss) % 9; \
    const int kh_ = tap_ / 3, kw_ = tap_ % 3; \
    _Pragma("unroll") \
    for (int ni = 0; ni < 4; ++ni) { \
      int pl = n0 + ni*16 + li; \
      int hh = pl >> 5, ww = pl & 31; \
      bg2[st][ni] = *(const bf16x8*)&Bs[cq_][hh + kh_][ww + kw_][quad * 8]; \
    } } while (0)

  LDA2(0, 0); LDB2(0, 0);                    // prologue: steps 0,1 in flight
  LDA2(1, 1); LDB2(1, 1);
#pragma unroll
  for (int s = 0; s < 36; ++s) {
    if (s < 34) { LDA2(s + 2, (s + 2) % 3); LDB2(s + 2, (s + 2) % 3); }
    __builtin_amdgcn_sched_barrier(0);       // pin issues above the MFMA cluster
#pragma unroll
    for (int mi = 0; mi < 4; ++mi)
#pragma unroll
      for (int ni = 0; ni < 4; ++ni)
        acc2[mi][ni] = __builtin_amdgcn_mfma_f32_16x16x32_bf16(af2[s % 3][mi], bg2[s % 3][ni], acc2[mi][ni], 0, 0, 0);
  }
#undef LDA2
#undef LDB2

  const float* qb = q + (size_t)b * QSTRIDE + WOFF;
  float* ob = out + (size_t)b * 128 * 1024 + p0;
#pragma unroll
  for (int mi = 0; mi < 4; ++mi) {
    int o0 = m0 + mi*16 + quad*4;
    float4 bias = *(const float4*)(qb + o0);
#pragma unroll
    for (int ni = 0; ni < 4; ++ni) {
      int pl = n0 + ni*16 + li;
      float* dp = ob + (size_t)o0 * 1024 + pl;
      f32x4 a = acc2[mi][ni];
      dp[0]    = a.x + bias.x;
      dp[1024] = a.y + bias.y;
      dp[2048] = a.z + bias.z;
      dp[3072] = a.w + bias.w;
    }
  }
}

extern "C" void kernel_launch(void* const* d_in, const int* in_sizes, int n_in,
                              void* d_out, int out_size, void* d_ws, size_t ws_size,
                              hipStream_t stream) {
  const float* q   = (const float*)d_in[0];
  const float* lhs = (const float*)d_in[1];
  const float* rhs = (const float*)d_in[2];
  const float* pw  = (const float*)d_in[3];
  const float* pb  = (const float*)d_in[4];
  float* out = (float*)d_out;

  // workspace layout (52,494,336 B used)
  char* ws = (char*)d_ws;
  ushort* wt2  = (ushort*)(ws);               // 18,874,368 B : wt2[b][tap][cq][o][32]
  ushort* pwb2 = (ushort*)(ws + 18874368);    //     65,536 B : pwb2[chunk][o][32]
  ushort* xt   = (ushort*)(ws + 18939904);    // 33,554,432 B : xt[b][c8][px1024][ch32]

  prep_kernel      <<<2064, 256, 0, stream>>>(q, pw, lhs, rhs, wt2, pwb2, xt);
  fused_conv_kernel<<<512,  256, 0, stream>>>(wt2, pwb2, xt, pb, q, out);
}